// Round 8
// baseline (151.059 us; speedup 1.0000x reference)
//
#include <hip/hip_runtime.h>

typedef unsigned short u16;
typedef unsigned int u32;
typedef __bf16 bf16x8 __attribute__((ext_vector_type(8)));
typedef float f32x4 __attribute__((ext_vector_type(4)));
typedef float f32x16 __attribute__((ext_vector_type(16)));
typedef u32 u32x2 __attribute__((ext_vector_type(2)));
typedef u32 u32x4 __attribute__((ext_vector_type(4)));

#define NB 4
#define NS 2048
#define ND 192
#define NH 8
#define HD 24
#define NM (NB*NS)          // 8192 rows
#define N3 (3*ND)           // 576
#define NBH (NB*NH)         // 32
#define NROWS (NBH*NS)      // 65536 partial rows per part
#define NCHUNK 72           // sum over g of ceil((g+1)/2)
#define MAXPART 8

#define LOG2E 1.4426950408889634f
// 1/sqrt(24) * log2(e): fold softmax scale and exp->exp2 conversion into Q
#define QSCALE (0.20412414523193152f * 1.4426950408889634f)

__device__ __forceinline__ u16 f2bf(float f){
  union { float f; unsigned u; } a; a.f = f;
  unsigned r = a.u + 0x7fffu + ((a.u >> 16) & 1u);   // round-to-nearest-even
  return (u16)(r >> 16);
}
__device__ __forceinline__ float b2f(u16 h){
  union { u32 u; float f; } a; a.u = ((u32)h) << 16; return a.f;
}
__device__ __forceinline__ u32 cvtpk(float lo, float hi){
  u32 r; asm("v_cvt_pk_bf16_f32 %0, %1, %2" : "=v"(r) : "v"(lo), "v"(hi)); return r;
}
// swaps high 32 lanes of a with low 32 lanes of b
__device__ __forceinline__ void pswap(u32 &a, u32 &b){
  asm("v_permlane32_swap_b32 %0, %1" : "+v"(a), "+v"(b));
}

// ---------------------------------------------------------------- prep ----
// weight transposes only: 36 blocks
__device__ __forceinline__ void transpose64(
    const float* __restrict__ src, int srcN, u16* __restrict__ dst, int dstK,
    int k0, int n0, u16 (*sh)[68], int tid)
{
  int r = tid >> 2, cs = tid & 3;
  const float* sp = src + (size_t)(k0 + r)*srcN + n0 + cs*16;
  #pragma unroll
  for (int q = 0; q < 4; ++q) {
    float4 v = *(const float4*)(sp + q*4);
    u16 o[4] = { f2bf(v.x), f2bf(v.y), f2bf(v.z), f2bf(v.w) };
    *(u32x2*)&sh[r][cs*16 + q*4] = *(const u32x2*)o;
  }
  __syncthreads();
  int n = tid >> 2, ks = tid & 3;
  u16 tmp[16];
  #pragma unroll
  for (int j = 0; j < 16; ++j) tmp[j] = sh[ks*16 + j][n];
  u16* dp = dst + (size_t)(n0 + n)*dstK + k0 + ks*16;
  *(u32x4*)dp       = *(const u32x4*)tmp;
  *(u32x4*)(dp + 8) = *(const u32x4*)(tmp + 8);
}

__global__ __launch_bounds__(256) void prep_kernel(
    const float* __restrict__ w_attn, const float* __restrict__ w_proj,
    u16* __restrict__ wta, u16* __restrict__ wtp)
{
  __shared__ u16 sh[64][68];
  const int bid = blockIdx.x, tid = threadIdx.x;
  if (bid < 27) {                                    // w_attn transpose
    int kt = bid/9, nt = bid%9;
    transpose64(w_attn, N3, wta, ND, kt*64, nt*64, sh, tid);
  } else {                                           // w_proj transpose
    int t = bid - 27; int kt = t/3, nt = t%3;
    transpose64(w_proj, ND, wtp, ND, kt*64, nt*64, sh, tid);
  }
}

// ----------------------------------------------------------------- qkv ----
// [8192,192] @ [192,576] + b.  96-wide n-tiles (4 heads exactly).
// x read as fp32, converted to bf16 A-frags inline (cvt_pk).
// Q/K -> qp/kp [b][h][s][32] (dense per-head rows; d24 = mask/1.0, pad=0)
// V   -> vtp [b][h][32][s]; row d=24 = 1.0 (denominator ones-row)
__global__ __launch_bounds__(256) void qkv_kernel(
    const float* __restrict__ x, const u16* __restrict__ wta,
    const float* __restrict__ b_attn, const float* __restrict__ mask0,
    u16* __restrict__ qp, u16* __restrict__ kp, u16* __restrict__ vtp)
{
  __shared__ u16 tile[96*72];    // V path: [96][72]; Q/K path: [64][104]
  const int m0 = blockIdx.x*64, n0 = blockIdx.y*96;
  const int tid = threadIdx.x;
  const int w = tid >> 6, lane = tid & 63, c = lane & 15, g = lane >> 4;
  f32x4 acc[6] = {};
  const int ar = m0 + w*16 + c;
  const float* xrow = x + (size_t)ar*ND;
  #pragma unroll
  for (int ks = 0; ks < 6; ++ks) {
    float4 xa = *(const float4*)(xrow + ks*32 + g*8);
    float4 xc = *(const float4*)(xrow + ks*32 + g*8 + 4);
    union { u32 wrd[4]; bf16x8 v; } afu;
    afu.wrd[0] = cvtpk(xa.x, xa.y); afu.wrd[1] = cvtpk(xa.z, xa.w);
    afu.wrd[2] = cvtpk(xc.x, xc.y); afu.wrd[3] = cvtpk(xc.z, xc.w);
    bf16x8 af = afu.v;
    #pragma unroll
    for (int t = 0; t < 6; ++t) {
      bf16x8 bfr = *(const bf16x8*)(wta + (size_t)(n0 + t*16 + c)*ND + ks*32 + g*8);
      acc[t] = __builtin_amdgcn_mfma_f32_16x16x32_bf16(af, bfr, acc[t], 0, 0, 0);
    }
  }
  const int b = m0 >> 11, sb = m0 & (NS-1);
  if (n0 >= 384) {                                   // ---- V tiles ----
    const int h0 = (n0 - 384)/HD;                    // 0 or 4
    #pragma unroll
    for (int t = 0; t < 6; ++t) {
      float bias = b_attn[n0 + t*16 + c];
      #pragma unroll
      for (int r = 0; r < 4; ++r)
        tile[(t*16 + c)*72 + w*16 + g*4 + r] = f2bf(acc[t][r] + bias);
    }
    __syncthreads();
    // dense stores: 8 rows x 128B per instruction
    const int chunk = tid & 7;
    u16 ones[8] = {0x3F80,0x3F80,0x3F80,0x3F80,0x3F80,0x3F80,0x3F80,0x3F80};
    #pragma unroll
    for (int rr = 0; rr < 4; ++rr) {
      int row = rr*32 + (tid >> 3);                  // 0..127
      if (row < 96) {
        int hl = row/HD, dv = row - hl*HD;
        u16* dst = vtp + ((size_t)((b*NH + h0 + hl)*32 + dv))*NS + sb + chunk*8;
        *(u32x4*)dst = *(const u32x4*)&tile[row*72 + chunk*8];
      } else if (row < 100) {
        int hl = row - 96;
        u16* dst = vtp + ((size_t)((b*NH + h0 + hl)*32 + 24))*NS + sb + chunk*8;
        *(u32x4*)dst = *(const u32x4*)ones;
      }
    }
  } else {                                           // ---- Q/K tiles ----
    const bool isQ = (n0 < 192);
    const float scl = isQ ? QSCALE : 1.0f;
    #pragma unroll
    for (int t = 0; t < 6; ++t) {
      float bias = b_attn[n0 + t*16 + c];
      #pragma unroll
      for (int r = 0; r < 4; ++r)
        tile[(w*16 + g*4 + r)*104 + t*16 + c] = f2bf((acc[t][r] + bias)*scl);
    }
    __syncthreads();
    int row = tid >> 2, run = tid & 3;
    int h0 = (n0 % 192)/HD;                          // 0 or 4
    u16 d24 = isQ ? (u16)0x3F80
                  : f2bf(mask0[b*NS + sb + row] * LOG2E);
    const u16* src = &tile[row*104 + run*24];        // 48B, 16B-aligned
    union { u32x4 q[4]; u16 s[32]; } buf;
    buf.q[0] = *(const u32x4*)(src);
    buf.q[1] = *(const u32x4*)(src + 8);
    buf.q[2] = *(const u32x4*)(src + 16);
    buf.s[24] = d24;
    #pragma unroll
    for (int j = 25; j < 32; ++j) buf.s[j] = 0;
    u16* dst = (isQ ? qp : kp)
             + ((size_t)((b*NH + h0 + run)*NS) + sb + row)*32;
    #pragma unroll
    for (int q = 0; q < 4; ++q)
      *(u32x4*)(dst + q*8) = buf.q[q];
  }
}

// ---------------------------------------------------------------- attn ----
// EQUAL-WORK chunks: each block = 4 kv-tiles (last chunk of a q-group: 2).
// blockIdx.x = chunk c in [0,72): triangular inverse gives (q-group g, part).
// 4 waves/block, 128 q-rows, K/V LDS-staged, double-buffered.
// Partials (unnorm O + l@d24, m) -> po[part]/pmf[part], part < (g+2)>>1.
__global__ __launch_bounds__(256) void attn_kernel(
    const u16* __restrict__ qp, const u16* __restrict__ kp,
    const u16* __restrict__ vtp, u16* __restrict__ po, float* __restrict__ pmf)
{
  __shared__ u16 klds[2][64][40];   // K tile: 64 rows, 80B stride (pad)
  __shared__ u16 vlds[2][32][72];   // V^T tile: 32 d-rows x 64 s, 144B stride

  const int chunk = blockIdx.x;
  const int bh = blockIdx.y;
  // triangular inverse: cum(2a)=a*a+a, cum(2a+1)=(a+1)^2
  int t = (int)sqrtf((float)chunk + 0.5f);
  while (t*t > chunk) --t;
  while ((t+1)*(t+1) <= chunk) ++t;
  const int g = (chunk < t*t + t) ? (2*t - 1) : (2*t);
  const int cumg = (g & 1) ? (((g-1)/2 + 1)*((g-1)/2 + 1)) : ((g/2)*(g/2) + g/2);
  const int part = chunk - cumg;
  const int t0 = part*4;                             // first kv tile (64-wide)
  const int cnt = min(4, 2*g + 2 - t0);              // 4 or 2 tiles

  const int tid = threadIdx.x;
  const int w = tid >> 6, lane = tid & 63, c = lane & 31, hi = lane >> 5;
  const int q0 = g*128 + w*32;

  const size_t qkbase = (size_t)bh*NS*32;            // [b][h][s][32]

  const u16* qrow = qp + qkbase + (size_t)(q0 + c)*32;
  bf16x8 qf0 = *(const bf16x8*)(qrow + hi*8);
  bf16x8 qf1 = *(const bf16x8*)(qrow + 16 + hi*8);

  // staging roles (block-wide)
  const int krow = tid >> 2, kch = tid & 3;          // K: 64 rows x 4x16B
  const int vrow = tid >> 3, vch = tid & 7;          // V: 32 rows x 8x16B
  const u16* kgsrc = kp + qkbase + (size_t)(t0*64 + krow)*32 + kch*8;
  const u16* vgsrc = vtp + ((size_t)(bh*32 + vrow))*NS + t0*64 + vch*8;

  f32x16 o = {0};
  const f32x16 z16 = {0};
  float m = 0.f;

  // prologue: stage first tile of this chunk
  u32x4 kreg = *(const u32x4*)(kgsrc);
  u32x4 vreg = *(const u32x4*)(vgsrc);
  *(u32x4*)&klds[0][krow][kch*8] = kreg;
  *(u32x4*)&vlds[0][vrow][vch*8] = vreg;
  __syncthreads();

  for (int dt = 0; dt < cnt; ++dt) {
    const int cur = dt & 1;
    if (dt + 1 < cnt) {                              // issue-early (T14)
      kreg = *(const u32x4*)(kgsrc + (size_t)(dt+1)*64*32);
      vreg = *(const u32x4*)(vgsrc + (dt+1)*64);
    }
    const int kb0 = (t0 + dt)*64;
    if (kb0 <= q0) {                                 // wave active this tile
      const bool a1 = (kb0 + 32 <= q0);              // chunk1 active
      // ---- QK^T chunk0 ----
      bf16x8 ka0 = *(const bf16x8*)&klds[cur][c][hi*8];
      bf16x8 ka1 = *(const bf16x8*)&klds[cur][c][16 + hi*8];
      __builtin_amdgcn_s_setprio(1);
      f32x16 st = __builtin_amdgcn_mfma_f32_32x32x16_bf16(ka0, qf0, z16, 0, 0, 0);
      st        = __builtin_amdgcn_mfma_f32_32x32x16_bf16(ka1, qf1, st,  0, 0, 0);
      __builtin_amdgcn_s_setprio(0);
      f32x16 su;
      if (a1) {                                      // ---- QK^T chunk1 ----
        bf16x8 kb0f = *(const bf16x8*)&klds[cur][32 + c][hi*8];
        bf16x8 kb1f = *(const bf16x8*)&klds[cur][32 + c][16 + hi*8];
        __builtin_amdgcn_s_setprio(1);
        su = __builtin_amdgcn_mfma_f32_32x32x16_bf16(kb0f, qf0, z16, 0, 0, 0);
        su = __builtin_amdgcn_mfma_f32_32x32x16_bf16(kb1f, qf1, su,  0, 0, 0);
        __builtin_amdgcn_s_setprio(0);
      }
      // ---- causal mask + per-lane max ----
      float pm = -3.0e38f;
      if (kb0 == q0) {                               // chunk0 is diagonal
        #pragma unroll
        for (int r = 0; r < 16; ++r) {
          int krel = (r & 3) + 8*(r >> 2) + 4*hi;
          float s = (krel > c) ? -3.0e38f : st[r];
          st[r] = s; pm = fmaxf(pm, s);
        }
      } else {
        #pragma unroll
        for (int r = 0; r < 16; ++r) pm = fmaxf(pm, st[r]);
      }
      if (a1) {
        if (kb0 + 32 == q0) {                        // chunk1 is diagonal
          #pragma unroll
          for (int r = 0; r < 16; ++r) {
            int krel = (r & 3) + 8*(r >> 2) + 4*hi;
            float s = (krel > c) ? -3.0e38f : su[r];
            su[r] = s; pm = fmaxf(pm, s);
          }
        } else {
          #pragma unroll
          for (int r = 0; r < 16; ++r) pm = fmaxf(pm, su[r]);
        }
      }
      // ---- defer-max online softmax ----
      if (!__all(pm - m <= 8.f)) {
        float pm2 = fmaxf(pm, __shfl_xor(pm, 32));
        float mn = fmaxf(m, pm2);
        float al = __builtin_amdgcn_exp2f(m - mn);
        #pragma unroll
        for (int r = 0; r < 16; ++r) o[r] *= al;
        m = mn;
      }
      #pragma unroll
      for (int r = 0; r < 16; ++r) st[r] = __builtin_amdgcn_exp2f(st[r] - m);
      if (a1) {
        #pragma unroll
        for (int r = 0; r < 16; ++r) su[r] = __builtin_amdgcn_exp2f(su[r] - m);
      }
      // ---- P^T -> B-frags (cvt_pk + permlane32_swap), PV chunk0 ----
      {
        u32 a0 = cvtpk(st[0], st[1]),  b0 = cvtpk(st[4], st[5]);
        u32 a1w = cvtpk(st[2], st[3]), b1 = cvtpk(st[6], st[7]);
        pswap(a0, b0); pswap(a1w, b1);
        u32 a2 = cvtpk(st[8], st[9]),  b2 = cvtpk(st[12], st[13]);
        u32 a3 = cvtpk(st[10], st[11]), b3 = cvtpk(st[14], st[15]);
        pswap(a2, b2); pswap(a3, b3);
        union { u32 wrd[4]; bf16x8 v; } pf0, pf1;
        pf0.wrd[0] = a0; pf0.wrd[1] = a1w; pf0.wrd[2] = b0; pf0.wrd[3] = b1;
        pf1.wrd[0] = a2; pf1.wrd[1] = a3;  pf1.wrd[2] = b2; pf1.wrd[3] = b3;
        bf16x8 va0 = *(const bf16x8*)&vlds[cur][c][hi*8];
        bf16x8 va1 = *(const bf16x8*)&vlds[cur][c][16 + hi*8];
        __builtin_amdgcn_s_setprio(1);
        o = __builtin_amdgcn_mfma_f32_32x32x16_bf16(va0, pf0.v, o, 0, 0, 0);
        o = __builtin_amdgcn_mfma_f32_32x32x16_bf16(va1, pf1.v, o, 0, 0, 0);
        __builtin_amdgcn_s_setprio(0);
      }
      if (a1) {                                      // ---- PV chunk1 ----
        u32 a0 = cvtpk(su[0], su[1]),  b0 = cvtpk(su[4], su[5]);
        u32 a1w = cvtpk(su[2], su[3]), b1 = cvtpk(su[6], su[7]);
        pswap(a0, b0); pswap(a1w, b1);
        u32 a2 = cvtpk(su[8], su[9]),  b2 = cvtpk(su[12], su[13]);
        u32 a3 = cvtpk(su[10], su[11]), b3 = cvtpk(su[14], su[15]);
        pswap(a2, b2); pswap(a3, b3);
        union { u32 wrd[4]; bf16x8 v; } pf0, pf1;
        pf0.wrd[0] = a0; pf0.wrd[1] = a1w; pf0.wrd[2] = b0; pf0.wrd[3] = b1;
        pf1.wrd[0] = a2; pf1.wrd[1] = a3;  pf1.wrd[2] = b2; pf1.wrd[3] = b3;
        bf16x8 va0 = *(const bf16x8*)&vlds[cur][c][32 + hi*8];
        bf16x8 va1 = *(const bf16x8*)&vlds[cur][c][48 + hi*8];
        __builtin_amdgcn_s_setprio(1);
        o = __builtin_amdgcn_mfma_f32_32x32x16_bf16(va0, pf0.v, o, 0, 0, 0);
        o = __builtin_amdgcn_mfma_f32_32x32x16_bf16(va1, pf1.v, o, 0, 0, 0);
        __builtin_amdgcn_s_setprio(0);
      }
    }
    // ---- write-late staging into the other buffer, then tile barrier ----
    if (dt + 1 < cnt) {
      *(u32x4*)&klds[cur^1][krow][kch*8] = kreg;
      *(u32x4*)&vlds[cur^1][vrow][vch*8] = vreg;
    }
    __syncthreads();
  }

  // ---- epilogue: write partial (l rides channel d=24; zeros if inactive) ----
  const int pidx = part*NROWS + bh*NS + q0 + c;
  u16* porow = po + (size_t)pidx*32;
  #pragma unroll
  for (int rr = 0; rr < 4; ++rr) {
    u32 lo = cvtpk(o[rr*4 + 0], o[rr*4 + 1]);
    u32 h2 = cvtpk(o[rr*4 + 2], o[rr*4 + 3]);
    u32x2 wv = {lo, h2};
    *(u32x2*)(porow + rr*8 + hi*4) = wv;
  }
  if (hi == 0) pmf[pidx] = (t0*64 <= q0) ? m : -3.0e38f;
}

// ---------------------------------------------------------------- proj ----
// merge of np=(g+2)>>1 kv-partials fused into the A-fragment build, then
// [8192,192] @ [192,192] + b -> out fp32
__global__ __launch_bounds__(256) void proj_kernel(
    const u16* __restrict__ po, const float* __restrict__ pmf,
    const u16* __restrict__ wtp, const float* __restrict__ bp,
    float* __restrict__ out)
{
  const int m0 = blockIdx.x*64, n0 = blockIdx.y*64;
  const int tid = threadIdx.x;
  const int w = tid >> 6, lane = tid & 63, c = lane & 15, gl = lane >> 4;
  const int ar = m0 + w*16 + c;
  const int b = ar >> 11, s = ar & (NS-1);
  const int np = ((s >> 7) + 2) >> 1;                // parts for this q-group

  // ---- build 6 A-frags by merging np partials on the fly ----
  bf16x8 af[6];
  #pragma unroll
  for (int ks = 0; ks < 6; ++ks) {
    int ch = ks*32 + gl*8;
    int h = ch / HD, dd = ch - h*HD;                 // 8-chunk lies in one head
    size_t ridx = (size_t)(b*NH + h)*NS + s;
    float M = -3.0e38f;
    for (int p = 0; p < np; ++p) M = fmaxf(M, pmf[(size_t)p*NROWS + ridx]);
    float v[8] = {}; float l = 0.f;
    for (int p = 0; p < np; ++p) {
      float wp = __builtin_amdgcn_exp2f(pmf[(size_t)p*NROWS + ridx] - M);
      const u16* rp = po + ((size_t)p*NROWS + ridx)*32;
      u32x4 pa = *(const u32x4*)(rp + dd);
      l += b2f(rp[24])*wp;
      #pragma unroll
      for (int jj = 0; jj < 4; ++jj) {
        u32 wa = pa[jj];
        v[jj*2]   += b2f((u16)(wa & 0xffff))*wp;
        v[jj*2+1] += b2f((u16)(wa >> 16))*wp;
      }
    }
    float inv = 1.0f / l;
    union { u32 wrd[4]; bf16x8 vv; } fu;
    #pragma unroll
    for (int jj = 0; jj < 4; ++jj)
      fu.wrd[jj] = cvtpk(v[jj*2]*inv, v[jj*2+1]*inv);
    af[ks] = fu.vv;
  }

  // ---- GEMM ----
  f32x4 acc[4] = {};
  #pragma unroll
  for (int ks = 0; ks < 6; ++ks) {
    #pragma unroll
    for (int t = 0; t < 4; ++t) {
      bf16x8 bfr = *(const bf16x8*)(wtp + (size_t)(n0 + t*16 + c)*ND + ks*32 + gl*8);
      acc[t] = __builtin_amdgcn_mfma_f32_16x16x32_bf16(af[ks], bfr, acc[t], 0, 0, 0);
    }
  }
  #pragma unroll
  for (int t = 0; t < 4; ++t) {
    int n = n0 + t*16 + c;
    float bias = bp[n];
    #pragma unroll
    for (int r = 0; r < 4; ++r) {
      int mm = m0 + w*16 + gl*4 + r;
      out[(size_t)mm*ND + n] = acc[t][r] + bias;
    }
  }
}

// -------------------------------------------------------------- launch ----
extern "C" void kernel_launch(void* const* d_in, const int* in_sizes, int n_in,
                              void* d_out, int out_size, void* d_ws, size_t ws_size,
                              hipStream_t stream)
{
  const float* x      = (const float*)d_in[0];
  const float* mask0  = (const float*)d_in[1];
  const float* w_attn = (const float*)d_in[2];
  const float* b_attn = (const float*)d_in[3];
  const float* w_proj = (const float*)d_in[4];
  const float* b_proj = (const float*)d_in[5];
  float* out = (float*)d_out;

  char* ws = (char*)d_ws;
  u16*   qp  = (u16*)(ws);                                  // 4 MB [b][h][s][32]
  u16*   kp  = (u16*)(ws + ((size_t)4  << 20));             // 4 MB [b][h][s][32]
  u16*   vtp = (u16*)(ws + ((size_t)8  << 20));             // 4 MB [b][h][32][s]
  u16*   wta = (u16*)(ws + ((size_t)12 << 20));             // 216 KB
  u16*   wtp = (u16*)(ws + ((size_t)12 << 20) + 256*1024);  // 72 KB
  u16*   po  = (u16*)(ws + ((size_t)13 << 20));             // 32 MB partials (8 slots)
  float* pmf = (float*)(ws + ((size_t)45 << 20));           // 2 MB running max
  // total ws use: 47 MB

  prep_kernel<<<36, 256, 0, stream>>>(w_attn, w_proj, wta, wtp);
  qkv_kernel<<<dim3(NM/64, 6), 256, 0, stream>>>(x, wta, b_attn, mask0,
                                                 qp, kp, vtp);
  attn_kernel<<<dim3(NCHUNK, NBH), 256, 0, stream>>>(qp, kp, vtp, po, pmf);
  proj_kernel<<<dim3(NM/64, ND/64), 256, 0, stream>>>(po, pmf, wtp, b_proj, out);
}

// Round 9
// 129.630 us; speedup vs baseline: 1.1653x; 1.1653x over previous
//
#include <hip/hip_runtime.h>

typedef unsigned short u16;
typedef unsigned int u32;
typedef __bf16 bf16x8 __attribute__((ext_vector_type(8)));
typedef float f32x4 __attribute__((ext_vector_type(4)));
typedef float f32x16 __attribute__((ext_vector_type(16)));
typedef u32 u32x2 __attribute__((ext_vector_type(2)));
typedef u32 u32x4 __attribute__((ext_vector_type(4)));

#define NB 4
#define NS 2048
#define ND 192
#define NH 8
#define HD 24
#define NM (NB*NS)          // 8192 rows
#define N3 (3*ND)           // 576
#define NBH (NB*NH)         // 32
#define NROWS (NBH*NS)      // 65536 partial rows per part
#define NPART 2

#define LOG2E 1.4426950408889634f
// 1/sqrt(24) * log2(e): fold softmax scale and exp->exp2 conversion into Q
#define QSCALE (0.20412414523193152f * 1.4426950408889634f)

__device__ __forceinline__ u16 f2bf(float f){
  union { float f; unsigned u; } a; a.f = f;
  unsigned r = a.u + 0x7fffu + ((a.u >> 16) & 1u);   // round-to-nearest-even
  return (u16)(r >> 16);
}
__device__ __forceinline__ float b2f(u16 h){
  union { u32 u; float f; } a; a.u = ((u32)h) << 16; return a.f;
}
__device__ __forceinline__ u32 cvtpk(float lo, float hi){
  u32 r; asm("v_cvt_pk_bf16_f32 %0, %1, %2" : "=v"(r) : "v"(lo), "v"(hi)); return r;
}
// swaps high 32 lanes of a with low 32 lanes of b
__device__ __forceinline__ void pswap(u32 &a, u32 &b){
  asm("v_permlane32_swap_b32 %0, %1" : "+v"(a), "+v"(b));
}

// ---------------------------------------------------------------- prep ----
// weight transposes only: 36 blocks
__device__ __forceinline__ void transpose64(
    const float* __restrict__ src, int srcN, u16* __restrict__ dst, int dstK,
    int k0, int n0, u16 (*sh)[68], int tid)
{
  int r = tid >> 2, cs = tid & 3;
  const float* sp = src + (size_t)(k0 + r)*srcN + n0 + cs*16;
  #pragma unroll
  for (int q = 0; q < 4; ++q) {
    float4 v = *(const float4*)(sp + q*4);
    u16 o[4] = { f2bf(v.x), f2bf(v.y), f2bf(v.z), f2bf(v.w) };
    *(u32x2*)&sh[r][cs*16 + q*4] = *(const u32x2*)o;
  }
  __syncthreads();
  int n = tid >> 2, ks = tid & 3;
  u16 tmp[16];
  #pragma unroll
  for (int j = 0; j < 16; ++j) tmp[j] = sh[ks*16 + j][n];
  u16* dp = dst + (size_t)(n0 + n)*dstK + k0 + ks*16;
  *(u32x4*)dp       = *(const u32x4*)tmp;
  *(u32x4*)(dp + 8) = *(const u32x4*)(tmp + 8);
}

__global__ __launch_bounds__(256) void prep_kernel(
    const float* __restrict__ w_attn, const float* __restrict__ w_proj,
    u16* __restrict__ wta, u16* __restrict__ wtp)
{
  __shared__ u16 sh[64][68];
  const int bid = blockIdx.x, tid = threadIdx.x;
  if (bid < 27) {                                    // w_attn transpose
    int kt = bid/9, nt = bid%9;
    transpose64(w_attn, N3, wta, ND, kt*64, nt*64, sh, tid);
  } else {                                           // w_proj transpose
    int t = bid - 27; int kt = t/3, nt = t%3;
    transpose64(w_proj, ND, wtp, ND, kt*64, nt*64, sh, tid);
  }
}

// ----------------------------------------------------------------- qkv ----
// [8192,192] @ [192,576] + b.  96-wide n-tiles (4 heads exactly).
// x read as fp32, converted to bf16 A-frags inline (cvt_pk).
// Q/K -> qp/kp [b][h][s][32] (dense per-head rows; d24 = mask/1.0, pad=0)
// V   -> vtp [b][h][32][s]; row d=24 = 1.0 (denominator ones-row)
__global__ __launch_bounds__(256) void qkv_kernel(
    const float* __restrict__ x, const u16* __restrict__ wta,
    const float* __restrict__ b_attn, const float* __restrict__ mask0,
    u16* __restrict__ qp, u16* __restrict__ kp, u16* __restrict__ vtp)
{
  __shared__ u16 tile[96*72];    // V path: [96][72]; Q/K path: [64][104]
  const int m0 = blockIdx.x*64, n0 = blockIdx.y*96;
  const int tid = threadIdx.x;
  const int w = tid >> 6, lane = tid & 63, c = lane & 15, g = lane >> 4;
  f32x4 acc[6] = {};
  const int ar = m0 + w*16 + c;
  const float* xrow = x + (size_t)ar*ND;
  #pragma unroll
  for (int ks = 0; ks < 6; ++ks) {
    float4 xa = *(const float4*)(xrow + ks*32 + g*8);
    float4 xc = *(const float4*)(xrow + ks*32 + g*8 + 4);
    union { u32 wrd[4]; bf16x8 v; } afu;
    afu.wrd[0] = cvtpk(xa.x, xa.y); afu.wrd[1] = cvtpk(xa.z, xa.w);
    afu.wrd[2] = cvtpk(xc.x, xc.y); afu.wrd[3] = cvtpk(xc.z, xc.w);
    bf16x8 af = afu.v;
    #pragma unroll
    for (int t = 0; t < 6; ++t) {
      bf16x8 bfr = *(const bf16x8*)(wta + (size_t)(n0 + t*16 + c)*ND + ks*32 + g*8);
      acc[t] = __builtin_amdgcn_mfma_f32_16x16x32_bf16(af, bfr, acc[t], 0, 0, 0);
    }
  }
  const int b = m0 >> 11, sb = m0 & (NS-1);
  if (n0 >= 384) {                                   // ---- V tiles ----
    const int h0 = (n0 - 384)/HD;                    // 0 or 4
    #pragma unroll
    for (int t = 0; t < 6; ++t) {
      float bias = b_attn[n0 + t*16 + c];
      #pragma unroll
      for (int r = 0; r < 4; ++r)
        tile[(t*16 + c)*72 + w*16 + g*4 + r] = f2bf(acc[t][r] + bias);
    }
    __syncthreads();
    // dense stores: 8 rows x 128B per instruction
    const int chunk = tid & 7;
    u16 ones[8] = {0x3F80,0x3F80,0x3F80,0x3F80,0x3F80,0x3F80,0x3F80,0x3F80};
    #pragma unroll
    for (int rr = 0; rr < 4; ++rr) {
      int row = rr*32 + (tid >> 3);                  // 0..127
      if (row < 96) {
        int hl = row/HD, dv = row - hl*HD;
        u16* dst = vtp + ((size_t)((b*NH + h0 + hl)*32 + dv))*NS + sb + chunk*8;
        *(u32x4*)dst = *(const u32x4*)&tile[row*72 + chunk*8];
      } else if (row < 100) {
        int hl = row - 96;
        u16* dst = vtp + ((size_t)((b*NH + h0 + hl)*32 + 24))*NS + sb + chunk*8;
        *(u32x4*)dst = *(const u32x4*)ones;
      }
    }
  } else {                                           // ---- Q/K tiles ----
    const bool isQ = (n0 < 192);
    const float scl = isQ ? QSCALE : 1.0f;
    #pragma unroll
    for (int t = 0; t < 6; ++t) {
      float bias = b_attn[n0 + t*16 + c];
      #pragma unroll
      for (int r = 0; r < 4; ++r)
        tile[(w*16 + g*4 + r)*104 + t*16 + c] = f2bf((acc[t][r] + bias)*scl);
    }
    __syncthreads();
    int row = tid >> 2, run = tid & 3;
    int h0 = (n0 % 192)/HD;                          // 0 or 4
    u16 d24 = isQ ? (u16)0x3F80
                  : f2bf(mask0[b*NS + sb + row] * LOG2E);
    const u16* src = &tile[row*104 + run*24];        // 48B, 16B-aligned
    union { u32x4 q[4]; u16 s[32]; } buf;
    buf.q[0] = *(const u32x4*)(src);
    buf.q[1] = *(const u32x4*)(src + 8);
    buf.q[2] = *(const u32x4*)(src + 16);
    buf.s[24] = d24;
    #pragma unroll
    for (int j = 25; j < 32; ++j) buf.s[j] = 0;
    u16* dst = (isQ ? qp : kp)
             + ((size_t)((b*NH + h0 + run)*NS) + sb + row)*32;
    #pragma unroll
    for (int q = 0; q < 4; ++q)
      *(u32x4*)(dst + q*8) = buf.q[q];
  }
}

// ---------------------------------------------------------------- attn ----
// 4 waves/block, 128 q-rows/block, kv-range split in 2 equal parts
// (g+1 tiles each). K/V staged in LDS, double-buffered, 1 barrier/tile.
// Partials (unnorm O + l@d24, m) -> po/pmf.
__global__ __launch_bounds__(256) void attn_kernel(
    const u16* __restrict__ qp, const u16* __restrict__ kp,
    const u16* __restrict__ vtp, u16* __restrict__ po, float* __restrict__ pmf)
{
  __shared__ u16 klds[2][64][40];   // K tile: 64 rows, 80B stride (pad)
  __shared__ u16 vlds[2][32][72];   // V^T tile: 32 d-rows x 64 s, 144B stride

  const int bh = blockIdx.x;
  const int g  = 15 - (int)blockIdx.y;               // heavy blocks first
  const int part = blockIdx.z;
  const int tid = threadIdx.x;
  const int w = tid >> 6, lane = tid & 63, c = lane & 31, hi = lane >> 5;
  const int q0 = g*128 + w*32;
  const int cnt = g + 1;                             // tiles per part
  const int t0 = part*cnt;

  const size_t qkbase = (size_t)bh*NS*32;            // [b][h][s][32]

  const u16* qrow = qp + qkbase + (size_t)(q0 + c)*32;
  bf16x8 qf0 = *(const bf16x8*)(qrow + hi*8);
  bf16x8 qf1 = *(const bf16x8*)(qrow + 16 + hi*8);

  // staging roles (block-wide)
  const int krow = tid >> 2, kch = tid & 3;          // K: 64 rows x 4x16B
  const int vrow = tid >> 3, vch = tid & 7;          // V: 32 rows x 8x16B
  const u16* kgsrc = kp + qkbase + (size_t)(t0*64 + krow)*32 + kch*8;
  const u16* vgsrc = vtp + ((size_t)(bh*32 + vrow))*NS + t0*64 + vch*8;

  f32x16 o = {0};
  const f32x16 z16 = {0};
  float m = 0.f;

  // prologue: stage first tile of this part
  u32x4 kreg = *(const u32x4*)(kgsrc);
  u32x4 vreg = *(const u32x4*)(vgsrc);
  *(u32x4*)&klds[0][krow][kch*8] = kreg;
  *(u32x4*)&vlds[0][vrow][vch*8] = vreg;
  __syncthreads();

  for (int dt = 0; dt < cnt; ++dt) {
    const int cur = dt & 1;
    if (dt + 1 < cnt) {                              // issue-early (T14)
      kreg = *(const u32x4*)(kgsrc + (size_t)(dt+1)*64*32);
      vreg = *(const u32x4*)(vgsrc + (dt+1)*64);
    }
    const int kb0 = (t0 + dt)*64;
    if (kb0 <= q0) {                                 // wave active this tile
      const bool a1 = (kb0 + 32 <= q0);              // chunk1 active
      // ---- QK^T chunk0 ----
      bf16x8 ka0 = *(const bf16x8*)&klds[cur][c][hi*8];
      bf16x8 ka1 = *(const bf16x8*)&klds[cur][c][16 + hi*8];
      __builtin_amdgcn_s_setprio(1);
      f32x16 st = __builtin_amdgcn_mfma_f32_32x32x16_bf16(ka0, qf0, z16, 0, 0, 0);
      st        = __builtin_amdgcn_mfma_f32_32x32x16_bf16(ka1, qf1, st,  0, 0, 0);
      __builtin_amdgcn_s_setprio(0);
      f32x16 su;
      if (a1) {                                      // ---- QK^T chunk1 ----
        bf16x8 kb0f = *(const bf16x8*)&klds[cur][32 + c][hi*8];
        bf16x8 kb1f = *(const bf16x8*)&klds[cur][32 + c][16 + hi*8];
        __builtin_amdgcn_s_setprio(1);
        su = __builtin_amdgcn_mfma_f32_32x32x16_bf16(kb0f, qf0, z16, 0, 0, 0);
        su = __builtin_amdgcn_mfma_f32_32x32x16_bf16(kb1f, qf1, su,  0, 0, 0);
        __builtin_amdgcn_s_setprio(0);
      }
      // ---- causal mask + per-lane max ----
      float pm = -3.0e38f;
      if (kb0 == q0) {                               // chunk0 is diagonal
        #pragma unroll
        for (int r = 0; r < 16; ++r) {
          int krel = (r & 3) + 8*(r >> 2) + 4*hi;
          float s = (krel > c) ? -3.0e38f : st[r];
          st[r] = s; pm = fmaxf(pm, s);
        }
      } else {
        #pragma unroll
        for (int r = 0; r < 16; ++r) pm = fmaxf(pm, st[r]);
      }
      if (a1) {
        if (kb0 + 32 == q0) {                        // chunk1 is diagonal
          #pragma unroll
          for (int r = 0; r < 16; ++r) {
            int krel = (r & 3) + 8*(r >> 2) + 4*hi;
            float s = (krel > c) ? -3.0e38f : su[r];
            su[r] = s; pm = fmaxf(pm, s);
          }
        } else {
          #pragma unroll
          for (int r = 0; r < 16; ++r) pm = fmaxf(pm, su[r]);
        }
      }
      // ---- defer-max online softmax ----
      if (!__all(pm - m <= 8.f)) {
        float pm2 = fmaxf(pm, __shfl_xor(pm, 32));
        float mn = fmaxf(m, pm2);
        float al = __builtin_amdgcn_exp2f(m - mn);
        #pragma unroll
        for (int r = 0; r < 16; ++r) o[r] *= al;
        m = mn;
      }
      #pragma unroll
      for (int r = 0; r < 16; ++r) st[r] = __builtin_amdgcn_exp2f(st[r] - m);
      if (a1) {
        #pragma unroll
        for (int r = 0; r < 16; ++r) su[r] = __builtin_amdgcn_exp2f(su[r] - m);
      }
      // ---- P^T -> B-frags (cvt_pk + permlane32_swap), PV chunk0 ----
      {
        u32 a0 = cvtpk(st[0], st[1]),  b0 = cvtpk(st[4], st[5]);
        u32 a1w = cvtpk(st[2], st[3]), b1 = cvtpk(st[6], st[7]);
        pswap(a0, b0); pswap(a1w, b1);
        u32 a2 = cvtpk(st[8], st[9]),  b2 = cvtpk(st[12], st[13]);
        u32 a3 = cvtpk(st[10], st[11]), b3 = cvtpk(st[14], st[15]);
        pswap(a2, b2); pswap(a3, b3);
        union { u32 wrd[4]; bf16x8 v; } pf0, pf1;
        pf0.wrd[0] = a0; pf0.wrd[1] = a1w; pf0.wrd[2] = b0; pf0.wrd[3] = b1;
        pf1.wrd[0] = a2; pf1.wrd[1] = a3;  pf1.wrd[2] = b2; pf1.wrd[3] = b3;
        bf16x8 va0 = *(const bf16x8*)&vlds[cur][c][hi*8];
        bf16x8 va1 = *(const bf16x8*)&vlds[cur][c][16 + hi*8];
        __builtin_amdgcn_s_setprio(1);
        o = __builtin_amdgcn_mfma_f32_32x32x16_bf16(va0, pf0.v, o, 0, 0, 0);
        o = __builtin_amdgcn_mfma_f32_32x32x16_bf16(va1, pf1.v, o, 0, 0, 0);
        __builtin_amdgcn_s_setprio(0);
      }
      if (a1) {                                      // ---- PV chunk1 ----
        u32 a0 = cvtpk(su[0], su[1]),  b0 = cvtpk(su[4], su[5]);
        u32 a1w = cvtpk(su[2], su[3]), b1 = cvtpk(su[6], su[7]);
        pswap(a0, b0); pswap(a1w, b1);
        u32 a2 = cvtpk(su[8], su[9]),  b2 = cvtpk(su[12], su[13]);
        u32 a3 = cvtpk(su[10], su[11]), b3 = cvtpk(su[14], su[15]);
        pswap(a2, b2); pswap(a3, b3);
        union { u32 wrd[4]; bf16x8 v; } pf0, pf1;
        pf0.wrd[0] = a0; pf0.wrd[1] = a1w; pf0.wrd[2] = b0; pf0.wrd[3] = b1;
        pf1.wrd[0] = a2; pf1.wrd[1] = a3;  pf1.wrd[2] = b2; pf1.wrd[3] = b3;
        bf16x8 va0 = *(const bf16x8*)&vlds[cur][c][32 + hi*8];
        bf16x8 va1 = *(const bf16x8*)&vlds[cur][c][48 + hi*8];
        __builtin_amdgcn_s_setprio(1);
        o = __builtin_amdgcn_mfma_f32_32x32x16_bf16(va0, pf0.v, o, 0, 0, 0);
        o = __builtin_amdgcn_mfma_f32_32x32x16_bf16(va1, pf1.v, o, 0, 0, 0);
        __builtin_amdgcn_s_setprio(0);
      }
    }
    // ---- write-late staging into the other buffer, then tile barrier ----
    if (dt + 1 < cnt) {
      *(u32x4*)&klds[cur^1][krow][kch*8] = kreg;
      *(u32x4*)&vlds[cur^1][vrow][vch*8] = vreg;
    }
    __syncthreads();
  }

  // ---- epilogue: write partial (l rides channel d=24; zeros if inactive) ----
  const int pidx = part*NROWS + bh*NS + q0 + c;
  u16* porow = po + (size_t)pidx*32;
  #pragma unroll
  for (int rr = 0; rr < 4; ++rr) {
    u32 lo = cvtpk(o[rr*4 + 0], o[rr*4 + 1]);
    u32 h2 = cvtpk(o[rr*4 + 2], o[rr*4 + 3]);
    u32x2 wv = {lo, h2};
    *(u32x2*)(porow + rr*8 + hi*4) = wv;
  }
  if (hi == 0) pmf[pidx] = (t0*64 <= q0) ? m : -3.0e38f;
}

// ---------------------------------------------------------------- proj ----
// merge of the 2 kv-partials fused into the A-fragment build, then
// [8192,192] @ [192,192] + b -> out fp32
__global__ __launch_bounds__(256) void proj_kernel(
    const u16* __restrict__ po, const float* __restrict__ pmf,
    const u16* __restrict__ wtp, const float* __restrict__ bp,
    float* __restrict__ out)
{
  const int m0 = blockIdx.x*64, n0 = blockIdx.y*64;
  const int tid = threadIdx.x;
  const int w = tid >> 6, lane = tid & 63, c = lane & 15, g = lane >> 4;
  const int ar = m0 + w*16 + c;
  const int b = ar >> 11, s = ar & (NS-1);

  // ---- build 6 A-frags by merging partials on the fly ----
  bf16x8 af[6];
  #pragma unroll
  for (int ks = 0; ks < 6; ++ks) {
    int ch = ks*32 + g*8;
    int h = ch / HD, dd = ch - h*HD;                 // 8-chunk lies in one head
    size_t ridx = (size_t)(b*NH + h)*NS + s;
    float m1 = pmf[ridx], m2 = pmf[NROWS + ridx];
    float M = fmaxf(m1, m2);
    float w1 = __builtin_amdgcn_exp2f(m1 - M);
    float w2 = __builtin_amdgcn_exp2f(m2 - M);
    const u16* r1 = po + ridx*32;
    const u16* r2 = po + ((size_t)NROWS + ridx)*32;
    u32x4 pa = *(const u32x4*)(r1 + dd);
    u32x4 pb = *(const u32x4*)(r2 + dd);
    float l = b2f(r1[24])*w1 + b2f(r2[24])*w2;
    float inv = 1.0f / l;
    float s1 = w1*inv, s2 = w2*inv;
    union { u32 wrd[4]; bf16x8 v; } fu;
    #pragma unroll
    for (int jj = 0; jj < 4; ++jj) {
      u32 wa = pa[jj], wb = pb[jj];
      float v0 = b2f((u16)(wa & 0xffff))*s1 + b2f((u16)(wb & 0xffff))*s2;
      float v1 = b2f((u16)(wa >> 16))*s1 + b2f((u16)(wb >> 16))*s2;
      fu.wrd[jj] = cvtpk(v0, v1);
    }
    af[ks] = fu.v;
  }

  // ---- GEMM ----
  f32x4 acc[4] = {};
  #pragma unroll
  for (int ks = 0; ks < 6; ++ks) {
    #pragma unroll
    for (int t = 0; t < 4; ++t) {
      bf16x8 bfr = *(const bf16x8*)(wtp + (size_t)(n0 + t*16 + c)*ND + ks*32 + g*8);
      acc[t] = __builtin_amdgcn_mfma_f32_16x16x32_bf16(af[ks], bfr, acc[t], 0, 0, 0);
    }
  }
  #pragma unroll
  for (int t = 0; t < 4; ++t) {
    int n = n0 + t*16 + c;
    float bias = bp[n];
    #pragma unroll
    for (int r = 0; r < 4; ++r) {
      int mm = m0 + w*16 + g*4 + r;
      out[(size_t)mm*ND + n] = acc[t][r] + bias;
    }
  }
}

// -------------------------------------------------------------- launch ----
extern "C" void kernel_launch(void* const* d_in, const int* in_sizes, int n_in,
                              void* d_out, int out_size, void* d_ws, size_t ws_size,
                              hipStream_t stream)
{
  const float* x      = (const float*)d_in[0];
  const float* mask0  = (const float*)d_in[1];
  const float* w_attn = (const float*)d_in[2];
  const float* b_attn = (const float*)d_in[3];
  const float* w_proj = (const float*)d_in[4];
  const float* b_proj = (const float*)d_in[5];
  float* out = (float*)d_out;

  char* ws = (char*)d_ws;
  u16*   qp  = (u16*)(ws);                                  // 4 MB [b][h][s][32]
  u16*   kp  = (u16*)(ws + ((size_t)4  << 20));             // 4 MB [b][h][s][32]
  u16*   vtp = (u16*)(ws + ((size_t)8  << 20));             // 4 MB [b][h][32][s]
  u16*   wta = (u16*)(ws + ((size_t)12 << 20));             // 216 KB
  u16*   wtp = (u16*)(ws + ((size_t)12 << 20) + 256*1024);  // 72 KB
  u16*   po  = (u16*)(ws + ((size_t)13 << 20));             // 8 MB partials (2 parts)
  float* pmf = (float*)(ws + ((size_t)21 << 20));           // 512 KB running max
  // total ws use: 21.5 MB

  prep_kernel<<<36, 256, 0, stream>>>(w_attn, w_proj, wta, wtp);
  qkv_kernel<<<dim3(NM/64, 6), 256, 0, stream>>>(x, wta, b_attn, mask0,
                                                 qp, kp, vtp);
  attn_kernel<<<dim3(NBH, 16, NPART), 256, 0, stream>>>(qp, kp, vtp, po, pmf);
  proj_kernel<<<dim3(NM/64, ND/64), 256, 0, stream>>>(po, pmf, wtp, b_proj, out);
}